// Round 2
// 2149.118 us; speedup vs baseline: 2.8894x; 2.8894x over previous
//
#include <hip/hip_runtime.h>
#include <math.h>

#define L_ 4
#define D_ 512
#define H_ 2048
#define V_ 32000
#define B_ 2
#define T_ 2048
#define BT_ 4096
#define EPS_ 1e-5f

typedef unsigned short u16;
typedef __attribute__((ext_vector_type(8))) short bf16x8;
typedef __attribute__((ext_vector_type(4))) float f32x4;
typedef __attribute__((ext_vector_type(4))) unsigned short u16x4;
typedef const __attribute__((address_space(1))) void* gas1_t;
typedef __attribute__((address_space(3))) void* las3_t;

__device__ __forceinline__ float geluf(float x) {
    return 0.5f * x * (1.0f + erff(x * 0.70710678118654752f));
}
__device__ __forceinline__ u16 f2bf(float x) {
    unsigned u = __float_as_uint(x);
    u += 0x7FFFu + ((u >> 16) & 1u);   // RNE
    return (u16)(u >> 16);
}
__device__ __forceinline__ float bf2f(u16 h) { return __uint_as_float(((unsigned)h) << 16); }
__device__ __forceinline__ void splitf(float x, u16 &h, u16 &l) {
    h = f2bf(x);
    l = f2bf(x - bf2f(h));             // x - bf16(x) exact in fp32
}

// ---------------- embedding gather ----------------
__global__ __launch_bounds__(256) void k_embed(const int* __restrict__ ids,
                                               const float* __restrict__ emb,
                                               float* __restrict__ x) {
    int idx = blockIdx.x * 256 + threadIdx.x;
    int row = idx >> 9;
    int col = idx & 511;
    x[idx] = emb[(long)ids[row] * D_ + col];
}

// ---------------- layernorm -> bf16 hi/lo ----------------
__global__ __launch_bounds__(256) void k_ln_hl(const float* __restrict__ x,
                                               const float* __restrict__ s,
                                               const float* __restrict__ b,
                                               u16* __restrict__ yh,
                                               u16* __restrict__ yl) {
    long row = blockIdx.x;
    const float* xr = x + row * D_;
    int c0 = threadIdx.x, c1 = threadIdx.x + 256;
    float v0 = xr[c0], v1 = xr[c1];
    float sum = v0 + v1;
    float sq  = v0 * v0 + v1 * v1;
    #pragma unroll
    for (int off = 32; off >= 1; off >>= 1) {
        sum += __shfl_down(sum, off);
        sq  += __shfl_down(sq, off);
    }
    __shared__ float smem[8];
    int lane = threadIdx.x & 63, wid = threadIdx.x >> 6;
    if (lane == 0) { smem[wid] = sum; smem[4 + wid] = sq; }
    __syncthreads();
    if (threadIdx.x == 0) {
        float ts = smem[0] + smem[1] + smem[2] + smem[3];
        float tq = smem[4] + smem[5] + smem[6] + smem[7];
        float mu = ts / D_;
        float var = tq / D_ - mu * mu;
        smem[0] = mu;
        smem[1] = rsqrtf(var + EPS_);
    }
    __syncthreads();
    float mu = smem[0], r = smem[1];
    u16 h, l;
    splitf((v0 - mu) * r * s[c0] + b[c0], h, l);
    yh[row * D_ + c0] = h; yl[row * D_ + c0] = l;
    splitf((v1 - mu) * r * s[c1] + b[c1], h, l);
    yh[row * D_ + c1] = h; yl[row * D_ + c1] = l;
}

// ---------------- d[row] = dot(xg[row], xn[row]) from hi/lo pairs ----------------
__global__ __launch_bounds__(256) void k_rowdot_hl(const u16* __restrict__ ah, const u16* __restrict__ al,
                                                   const u16* __restrict__ bh, const u16* __restrict__ bl,
                                                   float* __restrict__ dv) {
    long base = (long)blockIdx.x * D_;
    int c0 = threadIdx.x, c1 = threadIdx.x + 256;
    float a0 = bf2f(ah[base + c0]) + bf2f(al[base + c0]);
    float b0 = bf2f(bh[base + c0]) + bf2f(bl[base + c0]);
    float a1 = bf2f(ah[base + c1]) + bf2f(al[base + c1]);
    float b1 = bf2f(bh[base + c1]) + bf2f(bl[base + c1]);
    float v = a0 * b0 + a1 * b1;
    #pragma unroll
    for (int off = 32; off >= 1; off >>= 1) v += __shfl_down(v, off);
    __shared__ float sm[4];
    int lane = threadIdx.x & 63, wid = threadIdx.x >> 6;
    if (lane == 0) sm[wid] = v;
    __syncthreads();
    if (threadIdx.x == 0) dv[blockIdx.x] = sm[0] + sm[1] + sm[2] + sm[3];
}

// ------- softmax row IN PLACE: logits = 2*S - d[j]; row's 8KB becomes [P_hi | P_lo] -------
__global__ __launch_bounds__(256) void k_softmax_ip(float* __restrict__ S,
                                                    const float* __restrict__ dvec) {
    long row = blockIdx.x;
    int b = blockIdx.x >> 11;
    float* Sr = S + row * T_;
    const float* db = dvec + (long)b * T_;
    float lv[8];
    float mx = -3.4e38f;
    #pragma unroll
    for (int i = 0; i < 8; i++) {
        int j = threadIdx.x + i * 256;
        float t = 2.0f * Sr[j] - db[j];
        lv[i] = t;
        mx = fmaxf(mx, t);
    }
    __shared__ float sm[4], sm2[4];
    int lane = threadIdx.x & 63, wid = threadIdx.x >> 6;
    #pragma unroll
    for (int off = 32; off >= 1; off >>= 1) mx = fmaxf(mx, __shfl_down(mx, off));
    if (lane == 0) sm[wid] = mx;
    __syncthreads();
    mx = fmaxf(fmaxf(sm[0], sm[1]), fmaxf(sm[2], sm[3]));
    float ssum = 0.f;
    #pragma unroll
    for (int i = 0; i < 8; i++) { lv[i] = expf(lv[i] - mx); ssum += lv[i]; }
    #pragma unroll
    for (int off = 32; off >= 1; off >>= 1) ssum += __shfl_down(ssum, off);
    if (lane == 0) sm2[wid] = ssum;
    __syncthreads();                       // also orders all Sr reads before writes below
    ssum = sm2[0] + sm2[1] + sm2[2] + sm2[3];
    float inv = 1.0f / ssum;
    u16* pr = (u16*)Sr;                    // this row's own 8KB: [0,2048)=hi, [2048,4096)=lo
    #pragma unroll
    for (int i = 0; i < 8; i++) {
        int j = threadIdx.x + i * 256;
        u16 h, l;
        splitf(lv[i] * inv, h, l);
        pr[j] = h; pr[T_ + j] = l;
    }
}

// ---------------- bf16 hi/lo transpose: in[z][R][C] -> out[z][C][R] ----------------
__global__ __launch_bounds__(256) void k_trans_hl(const u16* __restrict__ ih, const u16* __restrict__ il,
                                                  u16* __restrict__ oh, u16* __restrict__ ol,
                                                  int R, int C) {
    __shared__ u16 th[32][33], tl[32][33];
    const long z = (long)blockIdx.z * R * C;
    int c0 = blockIdx.x * 32, r0 = blockIdx.y * 32;
    int tr = threadIdx.x >> 5, tc = threadIdx.x & 31;
    #pragma unroll
    for (int i = 0; i < 32; i += 8) {
        long idx = z + (long)(r0 + tr + i) * C + c0 + tc;
        th[tr + i][tc] = ih[idx];
        tl[tr + i][tc] = il[idx];
    }
    __syncthreads();
    #pragma unroll
    for (int i = 0; i < 32; i += 8) {
        long o = z + (long)(c0 + tr + i) * R + r0 + tc;
        oh[o] = th[tc][tr + i];
        ol[o] = tl[tc][tr + i];
    }
}

// ======================= bf16x3 GEMM, B^T bf16 hi/lo (activations) =======================
// C[M,N] (+)= (Ah+Al)[M,*] x (Bh+Bl)[N,*]^T via Ah*Bh + Al*Bh + Ah*Bl.  128 x 32*NF tile,
// BK=32, 4 waves. All strides ldA/ldB/sA/sB in u16 elements, sC in floats.
// EPI: 0=store f32, 3=accumulate f32
template <int NF, int EPI>
__global__ __launch_bounds__(256) void k_gemm3(
    const u16* __restrict__ Ah, const u16* __restrict__ Al,
    const u16* __restrict__ Bh, const u16* __restrict__ Bl,
    float* __restrict__ C,
    int M, int N, int K, int ldA, int ldB, long sA, long sB, long sC)
{
    constexpr int BN = 32 * NF;
    __shared__ __align__(16) u16 sAh[128 * 32], sAl[128 * 32], sBh[BN * 32], sBl[BN * 32];

    const int tid  = threadIdx.x;
    const int lane = tid & 63;
    const int wv   = tid >> 6;
    const int wm   = wv >> 1, wn = wv & 1;
    const long z   = blockIdx.z;
    const int m0   = blockIdx.x * 128;     // m fast -> B-panel L2 reuse
    const int n0   = blockIdx.y * BN;

    const u16* gsrc; u16* sdst; int nIss; long ld;
    if (wv == 0)      { gsrc = Ah + z * sA + (long)m0 * ldA; sdst = sAh; nIss = 8;       ld = ldA; }
    else if (wv == 1) { gsrc = Al + z * sA + (long)m0 * ldA; sdst = sAl; nIss = 8;       ld = ldA; }
    else if (wv == 2) { gsrc = Bh + z * sB + (long)n0 * ldB; sdst = sBh; nIss = BN / 16; ld = ldB; }
    else              { gsrc = Bl + z * sB + (long)n0 * ldB; sdst = sBl; nIss = BN / 16; ld = ldB; }

    const int lrow = lane >> 2;
    const int lgr  = (lane & 3) ^ ((lane >> 3) & 3);    // pre-swizzled source granule
    const u16* glane = gsrc + lrow * ld + lgr * 8;

    const int smask = ((lane & 15) >> 1) & 3;
    const int kg    = ((lane >> 4) ^ smask) * 8;        // swizzled read granule
    int aoff[4], boff[NF];
    #pragma unroll
    for (int i = 0; i < 4; i++)
        aoff[i] = (wm * 64 + i * 16 + (lane & 15)) * 32 + kg;
    #pragma unroll
    for (int j = 0; j < NF; j++)
        boff[j] = (wn * 16 * NF + j * 16 + (lane & 15)) * 32 + kg;

    f32x4 acc[4][NF];
    #pragma unroll
    for (int i = 0; i < 4; i++)
        #pragma unroll
        for (int j = 0; j < NF; j++) acc[i][j] = (f32x4){0.f, 0.f, 0.f, 0.f};

    for (int k0 = 0; k0 < K; k0 += 32) {
        const u16* gk = glane + k0;
        for (int i = 0; i < nIss; i++) {
            __builtin_amdgcn_global_load_lds((gas1_t)(gk + (long)i * 16 * ld),
                                             (las3_t)(sdst + i * 512), 16, 0, 0);
        }
        __syncthreads();

        bf16x8 ah[4], al[4], bh[NF], bl[NF];
        #pragma unroll
        for (int i = 0; i < 4; i++) {
            ah[i] = *(const bf16x8*)(sAh + aoff[i]);
            al[i] = *(const bf16x8*)(sAl + aoff[i]);
        }
        #pragma unroll
        for (int j = 0; j < NF; j++) {
            bh[j] = *(const bf16x8*)(sBh + boff[j]);
            bl[j] = *(const bf16x8*)(sBl + boff[j]);
        }
        #pragma unroll
        for (int i = 0; i < 4; i++)
            #pragma unroll
            for (int j = 0; j < NF; j++) {
                acc[i][j] = __builtin_amdgcn_mfma_f32_16x16x32_bf16(ah[i], bh[j], acc[i][j], 0, 0, 0);
                acc[i][j] = __builtin_amdgcn_mfma_f32_16x16x32_bf16(al[i], bh[j], acc[i][j], 0, 0, 0);
                acc[i][j] = __builtin_amdgcn_mfma_f32_16x16x32_bf16(ah[i], bl[j], acc[i][j], 0, 0, 0);
            }
        __syncthreads();
    }

    // C/D layout: col = lane&15, row = (lane>>4)*4 + reg  (m89-verified)
    const long cz = z * sC;
    const int rl = (lane >> 4) * 4;
    const int cl = lane & 15;
    #pragma unroll
    for (int i = 0; i < 4; i++)
        #pragma unroll
        for (int r = 0; r < 4; r++) {
            const long gr = m0 + wm * 64 + i * 16 + rl + r;
            #pragma unroll
            for (int j = 0; j < NF; j++) {
                const int gc = n0 + wn * 16 * NF + j * 16 + cl;
                const long off = cz + gr * N + gc;
                if constexpr (EPI == 0) C[off] = acc[i][j][r];
                else                    C[off] += acc[i][j][r];
            }
        }
}

// ======================= bf16x3 GEMM, B fp32 [K,N] (weights, staged+split in-kernel) ====
// A = hi/lo bf16 (global_load_lds, XOR swizzle); B = fp32 [K,N], reg-staged -> split ->
// transposed padded LDS tiles [col][k], stride 40 u16 (b128 reads 16B-aligned, 2-way = free).
// EPI: 1=bias+gelu->hi/lo, 2=bias+acc f32, 4=bias+store f32, 5=->hi/lo
template <int NF, int EPI>
__global__ __launch_bounds__(256) void k_gemm3w(
    const u16* __restrict__ Ah, const u16* __restrict__ Al,
    const float* __restrict__ Bf,
    float* __restrict__ C, u16* __restrict__ Ch, u16* __restrict__ Cl,
    const float* __restrict__ bias,
    int M, int N, int K, int ldA, int ldB)
{
    constexpr int BN = 32 * NF;
    constexpr int LB = 40;   // padded LDS col stride (u16); col*80B: b128-aligned, 2-way banks
    __shared__ __align__(16) u16 sAh[128 * 32], sAl[128 * 32];
    __shared__ __align__(16) u16 sBh[BN * LB], sBl[BN * LB];

    const int tid  = threadIdx.x;
    const int lane = tid & 63;
    const int wv   = tid >> 6;
    const int wm   = wv >> 1, wn = wv & 1;
    const int m0   = blockIdx.x * 128;     // m fast -> weight-panel L2 reuse
    const int n0   = blockIdx.y * BN;

    // A staging: wave wv loads stripes 2wv, 2wv+1 of hi and lo
    const int lrow = lane >> 2;
    const int lgr  = (lane & 3) ^ ((lane >> 3) & 3);
    const int s0   = wv * 2;
    const long ldAl = ldA;
    const u16* gAh = Ah + (m0 + s0 * 16 + lrow) * ldAl + lgr * 8;
    const u16* gAl = Al + (m0 + s0 * 16 + lrow) * ldAl + lgr * 8;
    const long ldA16 = ldAl * 16;

    // B staging: thread t: n-lane = t&31, k-quad = t>>5
    const int nl = tid & 31;
    const int kq = tid >> 5;
    const float* gB = Bf + (long)(kq * 4) * ldB + n0 + nl;

    const int smask = ((lane & 15) >> 1) & 3;
    const int kgA   = ((lane >> 4) ^ smask) * 8;
    const int kgB   = (lane >> 4) * 8;
    int aoff[4], boff[NF];
    #pragma unroll
    for (int i = 0; i < 4; i++)
        aoff[i] = (wm * 64 + i * 16 + (lane & 15)) * 32 + kgA;
    #pragma unroll
    for (int j = 0; j < NF; j++)
        boff[j] = (wn * 16 * NF + j * 16 + (lane & 15)) * LB + kgB;

    f32x4 acc[4][NF];
    #pragma unroll
    for (int i = 0; i < 4; i++)
        #pragma unroll
        for (int j = 0; j < NF; j++) acc[i][j] = (f32x4){0.f, 0.f, 0.f, 0.f};

    for (int k0 = 0; k0 < K; k0 += 32) {
        const u16* pAh = gAh + k0;
        const u16* pAl = gAl + k0;
        __builtin_amdgcn_global_load_lds((gas1_t)pAh,           (las3_t)(sAh + s0 * 512),       16, 0, 0);
        __builtin_amdgcn_global_load_lds((gas1_t)(pAh + ldA16), (las3_t)(sAh + s0 * 512 + 512), 16, 0, 0);
        __builtin_amdgcn_global_load_lds((gas1_t)pAl,           (las3_t)(sAl + s0 * 512),       16, 0, 0);
        __builtin_amdgcn_global_load_lds((gas1_t)(pAl + ldA16), (las3_t)(sAl + s0 * 512 + 512), 16, 0, 0);

        const float* pB = gB + (long)k0 * ldB;
        #pragma unroll
        for (int c = 0; c < NF; c++) {
            float v0 = pB[c * 32];
            float v1 = pB[(long)ldB + c * 32];
            float v2 = pB[2L * ldB + c * 32];
            float v3 = pB[3L * ldB + c * 32];
            u16 h0, l0, h1, l1, h2, l2, h3, l3;
            splitf(v0, h0, l0); splitf(v1, h1, l1);
            splitf(v2, h2, l2); splitf(v3, h3, l3);
            const int n = c * 32 + nl;
            *(u16x4*)(sBh + n * LB + kq * 4) = (u16x4){h0, h1, h2, h3};
            *(u16x4*)(sBl + n * LB + kq * 4) = (u16x4){l0, l1, l2, l3};
        }
        __syncthreads();

        bf16x8 ah[4], al[4], bh[NF], bl[NF];
        #pragma unroll
        for (int i = 0; i < 4; i++) {
            ah[i] = *(const bf16x8*)(sAh + aoff[i]);
            al[i] = *(const bf16x8*)(sAl + aoff[i]);
        }
        #pragma unroll
        for (int j = 0; j < NF; j++) {
            bh[j] = *(const bf16x8*)(sBh + boff[j]);
            bl[j] = *(const bf16x8*)(sBl + boff[j]);
        }
        #pragma unroll
        for (int i = 0; i < 4; i++)
            #pragma unroll
            for (int j = 0; j < NF; j++) {
                acc[i][j] = __builtin_amdgcn_mfma_f32_16x16x32_bf16(ah[i], bh[j], acc[i][j], 0, 0, 0);
                acc[i][j] = __builtin_amdgcn_mfma_f32_16x16x32_bf16(al[i], bh[j], acc[i][j], 0, 0, 0);
                acc[i][j] = __builtin_amdgcn_mfma_f32_16x16x32_bf16(ah[i], bl[j], acc[i][j], 0, 0, 0);
            }
        __syncthreads();
    }

    const int rl = (lane >> 4) * 4;
    const int cl = lane & 15;
    #pragma unroll
    for (int i = 0; i < 4; i++)
        #pragma unroll
        for (int r = 0; r < 4; r++) {
            const long gr = m0 + wm * 64 + i * 16 + rl + r;
            #pragma unroll
            for (int j = 0; j < NF; j++) {
                const int gc = n0 + wn * 16 * NF + j * 16 + cl;
                const long off = gr * N + gc;
                float v = acc[i][j][r];
                if constexpr (EPI == 1) {
                    v = geluf(v + bias[gc]);
                    u16 h, lo; splitf(v, h, lo);
                    Ch[off] = h; Cl[off] = lo;
                } else if constexpr (EPI == 2) {
                    C[off] += v + bias[gc];
                } else if constexpr (EPI == 4) {
                    C[off] = v + bias[gc];
                } else {  // 5
                    u16 h, lo; splitf(v, h, lo);
                    Ch[off] = h; Cl[off] = lo;
                }
            }
        }
}

extern "C" void kernel_launch(void* const* d_in, const int* in_sizes, int n_in,
                              void* d_out, int out_size, void* d_ws, size_t ws_size,
                              hipStream_t stream) {
    const int*   ids   = (const int*)d_in[0];
    const float* embed = (const float*)d_in[1];
    const float* g     = (const float*)d_in[2];
    const float* W1    = (const float*)d_in[3];
    const float* b1    = (const float*)d_in[4];
    const float* W2    = (const float*)d_in[5];
    const float* b2    = (const float*)d_in[6];
    const float* ln1s  = (const float*)d_in[7];
    const float* ln1b  = (const float*)d_in[8];
    const float* ln2s  = (const float*)d_in[9];
    const float* ln2b  = (const float*)d_in[10];
    const float* lnfs  = (const float*)d_in[11];
    const float* lnfb  = (const float*)d_in[12];
    const float* headw = (const float*)d_in[13];
    const float* headb = (const float*)d_in[14];
    float* out = (float*)d_out;
    (void)in_sizes; (void)n_in; (void)out_size; (void)ws_size;

    // workspace: 58,736,640 B — identical to the previously-proven footprint
    char* w = (char*)d_ws;
    float* x  = (float*)w;  w += (long)BT_ * D_ * 4;   // residual fp32         8,388,608
    u16* xnh  = (u16*)w;    w += (long)BT_ * D_ * 2;   // LN out hi             4,194,304
    u16* xnl  = (u16*)w;    w += (long)BT_ * D_ * 2;   // LN out lo             4,194,304
    u16* xgh  = (u16*)w;    w += (long)BT_ * D_ * 2;   // xg hi / xn^T hi       4,194,304
    u16* xgl  = (u16*)w;    w += (long)BT_ * D_ * 2;   // xg lo / xn^T lo       4,194,304
    float* dv = (float*)w;  w += 16384;                // row dots              16,384
    float* S  = (float*)w;                             // scores/P/h           33,554,432

    u16* hh = (u16*)S;                 // FFN hidden hi (S dead during FFN)
    u16* hl = hh + (long)BT_ * H_;     // FFN hidden lo

    k_embed<<<dim3(BT_ * D_ / 256), 256, 0, stream>>>(ids, embed, x);

    for (int l = 0; l < L_; l++) {
        // --- attention ---
        k_ln_hl<<<BT_, 256, 0, stream>>>(x, ln1s + l * D_, ln1b + l * D_, xnh, xnl);
        // xg = xn @ g[l]          (B fp32 [D,D] direct)
        k_gemm3w<2, 5><<<dim3(BT_ / 128, D_ / 64), 256, 0, stream>>>(
            xnh, xnl, g + (long)l * D_ * D_, nullptr, xgh, xgl, nullptr,
            BT_, D_, D_, D_, D_);
        k_rowdot_hl<<<BT_, 256, 0, stream>>>(xgh, xgl, xnh, xnl, dv);
        // S_b = xg_b @ xn_b^T
        k_gemm3<4, 0><<<dim3(T_ / 128, T_ / 128, B_), 256, 0, stream>>>(
            xgh, xgl, xnh, xnl, S,
            T_, T_, D_, D_, D_, (long)T_ * D_, (long)T_ * D_, (long)T_ * T_);
        // xn^T into xg buffers (xg dead after S-gemm)
        k_trans_hl<<<dim3(D_ / 32, T_ / 32, B_), 256, 0, stream>>>(xnh, xnl, xgh, xgl, T_, D_);
        // softmax in place: each S row becomes [P_hi(2048 u16) | P_lo(2048 u16)]
        k_softmax_ip<<<BT_, 256, 0, stream>>>(S, dv);
        // x_b += P_b @ xn_b      (A = P in S: ldA = 2T u16, lo at +T)
        k_gemm3<2, 3><<<dim3(T_ / 128, D_ / 64, B_), 256, 0, stream>>>(
            (const u16*)S, (const u16*)S + T_, xgh, xgl, x,
            T_, D_, T_, 2 * T_, T_, (long)T_ * 2 * T_, (long)D_ * T_, (long)T_ * D_);

        // --- ffn ---
        k_ln_hl<<<BT_, 256, 0, stream>>>(x, ln2s + l * D_, ln2b + l * D_, xnh, xnl);
        // h = gelu(xn @ W1 + b1)  (B fp32 [D,H] direct) -> hi/lo in S region
        k_gemm3w<4, 1><<<dim3(BT_ / 128, H_ / 128), 256, 0, stream>>>(
            xnh, xnl, W1 + (long)l * D_ * H_, nullptr, hh, hl, b1 + l * H_,
            BT_, H_, D_, D_, H_);
        // x += h @ W2 + b2        (B fp32 [H,D] direct)
        k_gemm3w<2, 2><<<dim3(BT_ / 128, D_ / 64), 256, 0, stream>>>(
            hh, hl, W2 + (long)l * H_ * D_, x, nullptr, nullptr, b2 + l * D_,
            BT_, D_, H_, H_, D_);
    }

    // --- head ---
    k_ln_hl<<<BT_, 256, 0, stream>>>(x, lnfs, lnfb, xnh, xnl);
    // out = xf @ head_w + head_b  (B fp32 [D,V] direct)
    k_gemm3w<4, 4><<<dim3(BT_ / 128, V_ / 128), 256, 0, stream>>>(
        xnh, xnl, headw, out, nullptr, nullptr, headb,
        BT_, V_, D_, D_, V_);
}